// Round 7
// baseline (31.235 us; speedup 1.0000x reference)
//
#include <hip/hip_runtime.h>

#define IMG_H 1024
#define IMG_W 1024

// Streaming Sobel block-variance loss, shuffle-halo edition.
// 4096 waves = 16 images x 2 col-strips (512 cols) x 128 row-bands (8 rows).
// Each lane owns 8 cols (2 float4 per image per row). Horizontal halos come
// from neighbor lanes via shuffles; only the strip-boundary column needs a
// wave-uniform scalar load (1 cache line). Rolling separable Sobel with
// 3-row hA/hB carries; one 4x4 block variance finalized every 4 rows.

struct Row { float4 qa0, qa1, qb0, qb1; float ea, eb; };

__global__ __launch_bounds__(256) void gvl_main(const float* __restrict__ A,
                                                const float* __restrict__ B,
                                                float* __restrict__ partial) {
    const int t    = threadIdx.x;
    const int wave = (blockIdx.x << 2) | (t >> 6);   // 0..4095
    const int lane = t & 63;
    const int img   = wave >> 8;                     // 0..15
    const int rem   = wave & 255;
    const int band  = rem >> 1;                      // 0..127, 8 rows each
    const int strip = rem & 1;                       // 0..1, 512 cols each
    const int y0    = band << 3;
    const int c0    = (strip << 9) | (lane << 3);    // lane's first col
    const int ecol  = strip ? 511 : 512;             // strip-boundary column

    const float* __restrict__ Ab = A + (size_t)img * (size_t)(IMG_H * IMG_W);
    const float* __restrict__ Bb = B + (size_t)img * (size_t)(IMG_H * IMG_W);

    const float eLs = strip ? 1.f : 0.f;   // lane 0 left-halo: boundary col or img edge
    const float eRs = strip ? 0.f : 1.f;   // lane 63 right-halo
    const float maskPrev = (band > 0)    ? 1.f : 0.f;
    const float zlast    = (band == 127) ? 0.f : 1.f;

    auto load_row = [&](int y, Row& R) {
        int yc = y < 0 ? 0 : (y > IMG_H - 1 ? IMG_H - 1 : y);
        const float* ra = Ab + (size_t)yc * IMG_W;
        const float* rb = Bb + (size_t)yc * IMG_W;
        R.qa0 = *reinterpret_cast<const float4*>(ra + c0);
        R.qa1 = *reinterpret_cast<const float4*>(ra + c0 + 4);
        R.qb0 = *reinterpret_cast<const float4*>(rb + c0);
        R.qb1 = *reinterpret_cast<const float4*>(rb + c0 + 4);
        R.ea  = ra[ecol];   // wave-uniform address -> broadcast load
        R.eb  = rb[ecol];
    };

    // carries: hA (X) and hB (B) of prev-2 / prev-1 input rows, per image
    float aX2[8], aX1[8], aB2[8], aB1[8];
    float bX2[8], bX1[8], bB2[8], bB1[8];
    float sX[2][2], sXX[2][2], sY[2][2], sYY[2][2];
#pragma unroll
    for (int i = 0; i < 2; ++i)
#pragma unroll
        for (int j = 0; j < 2; ++j) { sX[i][j] = sXX[i][j] = sY[i][j] = sYY[i][j] = 0.f; }

    auto calc_h = [&](const float4 q0, const float4 q1, float e, float m,
                      float (&hX)[8], float (&hB)[8]) {
        float lv = __shfl_up(q1.w, 1);
        float rv = __shfl_down(q0.x, 1);
        lv = (lane == 0)  ? e * eLs : lv;
        rv = (lane == 63) ? e * eRs : rv;
        float w[10] = {lv, q0.x, q0.y, q0.z, q0.w, q1.x, q1.y, q1.z, q1.w, rv};
#pragma unroll
        for (int c = 0; c < 8; ++c) {
            hX[c] = (w[c + 2] - w[c]) * m;
            hB[c] = (w[c] + 2.f * w[c + 1] + w[c + 2]) * m;
        }
    };

    auto proc_img = [&](const float4 q0, const float4 q1, float e, float m,
                        float (&X2)[8], float (&X1)[8], float (&B2)[8], float (&B1)[8],
                        float (&sXi)[2], float (&sXXi)[2],
                        float (&sYi)[2], float (&sYYi)[2]) {
        float lv = __shfl_up(q1.w, 1);
        float rv = __shfl_down(q0.x, 1);
        lv = (lane == 0)  ? e * eLs : lv;
        rv = (lane == 63) ? e * eRs : rv;
        float w[10] = {lv, q0.x, q0.y, q0.z, q0.w, q1.x, q1.y, q1.z, q1.w, rv};
#pragma unroll
        for (int c = 0; c < 8; ++c) {
            float hX = (w[c + 2] - w[c]) * m;
            float hB = (w[c] + 2.f * w[c + 1] + w[c + 2]) * m;
            float gx = X2[c] + 2.f * X1[c] + hX;   // vertical [1,2,1]
            float gy = hB - B2[c];                 // vertical [-1,0,1]
            const int blk = c >> 2;
            sXi[blk] += gx;  sXXi[blk] += gx * gx;
            sYi[blk] += gy;  sYYi[blk] += gy * gy;
            X2[c] = X1[c];  X1[c] = hX;
            B2[c] = B1[c];  B1[c] = hB;
        }
    };

    float loss = 0.f;
    auto finalize = [&]() {
#pragma unroll
        for (int j = 0; j < 2; ++j) {
            float mXa = sX[0][j] * 0.0625f, mYa = sY[0][j] * 0.0625f;
            float vXa = sXX[0][j] * 0.0625f - mXa * mXa;
            float vYa = sYY[0][j] * 0.0625f - mYa * mYa;
            float mXb = sX[1][j] * 0.0625f, mYb = sY[1][j] * 0.0625f;
            float vXb = sXX[1][j] * 0.0625f - mXb * mXb;
            float vYb = sYY[1][j] * 0.0625f - mYb * mYb;
            float dX = vXa - vXb, dY = vYa - vYb;
            loss += dX * dX + dY * dY;
#pragma unroll
            for (int i = 0; i < 2; ++i) { sX[i][j] = sXX[i][j] = sY[i][j] = sYY[i][j] = 0.f; }
        }
    };

    // ---- prologue: rows y0-1, y0 into carries; prefetch row y0+1 ----
    Row Rm, R0, Rb0, Rb1;
    load_row(y0 - 1, Rm);
    load_row(y0,     R0);
    load_row(y0 + 1, Rb0);
    calc_h(Rm.qa0, Rm.qa1, Rm.ea, maskPrev, aX2, aB2);
    calc_h(Rm.qb0, Rm.qb1, Rm.eb, maskPrev, bX2, bB2);
    calc_h(R0.qa0, R0.qa1, R0.ea, 1.f, aX1, aB1);
    calc_h(R0.qb0, R0.qb1, R0.eb, 1.f, bX1, bB1);

    // ---- 8 input rows y0+1..y0+8, 1-row lookahead, fully unrolled ----
#pragma unroll
    for (int k = 0; k < 8; ++k) {
        Row& cur = (k & 1) ? Rb1 : Rb0;
        Row& nxt = (k & 1) ? Rb0 : Rb1;
        if (k < 7) load_row(y0 + 2 + k, nxt);
        const float m = (k == 7) ? zlast : 1.f;
        proc_img(cur.qa0, cur.qa1, cur.ea, m, aX2, aX1, aB2, aB1,
                 sX[0], sXX[0], sY[0], sYY[0]);
        proc_img(cur.qb0, cur.qb1, cur.eb, m, bX2, bX1, bB2, bB1,
                 sX[1], sXX[1], sY[1], sYY[1]);
        if ((k & 3) == 3) finalize();
    }

    // ---- wave reduction, one partial per wave ----
#pragma unroll
    for (int off = 32; off > 0; off >>= 1) loss += __shfl_down(loss, off);
    if (lane == 0) partial[wave] = loss;
}

__global__ __launch_bounds__(256) void gvl_final(const float* __restrict__ partial,
                                                 float* __restrict__ out) {
    int t = threadIdx.x;
    float s = 0.f;
#pragma unroll
    for (int i = 0; i < 16; ++i) s += partial[t + (i << 8)];
#pragma unroll
    for (int off = 32; off > 0; off >>= 1) s += __shfl_down(s, off);
    __shared__ float ws[4];
    if ((t & 63) == 0) ws[t >> 6] = s;
    __syncthreads();
    if (t == 0) out[0] = ws[0] + ws[1] + ws[2] + ws[3];
}

extern "C" void kernel_launch(void* const* d_in, const int* in_sizes, int n_in,
                              void* d_out, int out_size, void* d_ws, size_t ws_size,
                              hipStream_t stream) {
    const float* out_img = (const float*)d_in[0];
    const float* tgt_img = (const float*)d_in[1];
    float* partial = (float*)d_ws;   // 4096 floats = 16 KB
    gvl_main<<<1024, 256, 0, stream>>>(out_img, tgt_img, partial);
    gvl_final<<<1, 256, 0, stream>>>(partial, (float*)d_out);
}

// Round 8
// 29.516 us; speedup vs baseline: 1.0582x; 1.0582x over previous
//
#include <hip/hip_runtime.h>

#define IMG_H 1024
#define IMG_W 1024

// Inline-asm MLP streaming Sobel block-variance loss.
// 2048 waves = 16 img x 2 strips (512 cols) x 64 bands (16 rows).
// Lane owns 8 cols (2 float4/img/row); halos via shuffles; strip-boundary
// cols 511/512 via one wave-uniform dwordx2 per img per row.
// ALL vmem through asm volatile -> issue order pinned, 3-row lookahead,
// counted s_waitcnt vmcnt(N) + sched_barrier(0) per row (compiler cannot
// serialize this pipeline). Rolling separable Sobel carries (hX,hB).

struct Row { float4 a0, a1, b0, b1; float2 ea, eb; };

__device__ __forceinline__ float4 gload4(const float* p) {
    float4 d;
    asm volatile("global_load_dwordx4 %0, %1, off" : "=v"(d) : "v"(p));
    return d;
}
__device__ __forceinline__ float2 gload2(const float* p) {
    float2 d;
    asm volatile("global_load_dwordx2 %0, %1, off" : "=v"(d) : "v"(p));
    return d;
}
template <int N> __device__ __forceinline__ void waitv() {
    if constexpr (N >= 3)      asm volatile("s_waitcnt vmcnt(18)" ::: "memory");
    else if constexpr (N == 2) asm volatile("s_waitcnt vmcnt(12)" ::: "memory");
    else if constexpr (N == 1) asm volatile("s_waitcnt vmcnt(6)" ::: "memory");
    else                       asm volatile("s_waitcnt vmcnt(0)" ::: "memory");
    __builtin_amdgcn_sched_barrier(0);
}

__global__ __launch_bounds__(256, 2) void gvl_main(const float* __restrict__ A,
                                                   const float* __restrict__ B,
                                                   float* __restrict__ partial) {
    const int t    = threadIdx.x;
    const int wave = (blockIdx.x << 2) | (t >> 6);   // 0..2047
    const int lane = t & 63;
    const int img   = wave >> 7;                     // 0..15
    const int rem   = wave & 127;
    const int band  = rem >> 1;                      // 0..63, 16 rows
    const int strip = rem & 1;                       // 0..1, 512 cols
    const int y0    = band << 4;
    const int c0    = (strip << 9) | (lane << 3);

    const float* __restrict__ Ab = A + (size_t)img * (size_t)(IMG_H * IMG_W);
    const float* __restrict__ Bb = B + (size_t)img * (size_t)(IMG_H * IMG_W);

    const float m0  = (band == 0)  ? 0.f : 1.f;   // input row y=-1
    const float m17 = (band == 63) ? 0.f : 1.f;   // input row y=1024
    const bool  s1  = (strip == 1);

    Row Rb[4];
    auto issue_row = [&](int i, Row& R) {
        int y  = y0 - 1 + i;
        int yc = y < 0 ? 0 : (y > IMG_H - 1 ? IMG_H - 1 : y);
        const float* ra = Ab + ((size_t)yc << 10);
        const float* rb = Bb + ((size_t)yc << 10);
        R.a0 = gload4(ra + c0);
        R.a1 = gload4(ra + c0 + 4);
        R.b0 = gload4(rb + c0);
        R.b1 = gload4(rb + c0 + 4);
        R.ea = gload2(ra + 511);   // cols 511,512 (uniform -> 1 line)
        R.eb = gload2(rb + 511);
    };

    float hX2[2][8], hX1[2][8], hB2[2][8], hB1[2][8];
    float sX[2][2], sXX[2][2], sY[2][2], sYY[2][2];
#pragma unroll
    for (int i = 0; i < 2; ++i)
#pragma unroll
        for (int j = 0; j < 2; ++j) { sX[i][j] = sXX[i][j] = sY[i][j] = sYY[i][j] = 0.f; }

    float loss = 0.f;
    auto finalize = [&]() {
#pragma unroll
        for (int j = 0; j < 2; ++j) {
            float mXa = sX[0][j] * 0.0625f, mYa = sY[0][j] * 0.0625f;
            float vXa = sXX[0][j] * 0.0625f - mXa * mXa;
            float vYa = sYY[0][j] * 0.0625f - mYa * mYa;
            float mXb = sX[1][j] * 0.0625f, mYb = sY[1][j] * 0.0625f;
            float vXb = sXX[1][j] * 0.0625f - mXb * mXb;
            float vYb = sYY[1][j] * 0.0625f - mYb * mYb;
            float dX = vXa - vXb, dY = vYa - vYb;
            loss += dX * dX + dY * dY;
#pragma unroll
            for (int i = 0; i < 2; ++i) { sX[i][j] = sXX[i][j] = sY[i][j] = sYY[i][j] = 0.f; }
        }
    };

    auto consume_img = [&](int im, const float4 q0, const float4 q1,
                           const float2 e, float m, bool emit) {
        float lvr = __shfl_up(q1.w, 1);
        float rvr = __shfl_down(q0.x, 1);
        float eL = s1 ? e.x : 0.f;
        float eR = s1 ? 0.f : e.y;
        float lv = (lane == 0)  ? eL : lvr;
        float rv = (lane == 63) ? eR : rvr;
        float w[10] = {lv, q0.x, q0.y, q0.z, q0.w, q1.x, q1.y, q1.z, q1.w, rv};
#pragma unroll
        for (int c = 0; c < 8; ++c) {
            float hX0 = (w[c + 2] - w[c]) * m;
            float hB0 = (w[c] + 2.f * w[c + 1] + w[c + 2]) * m;
            if (emit) {
                float gx = hX2[im][c] + 2.f * hX1[im][c] + hX0;   // vert [1,2,1]
                float gy = hB0 - hB2[im][c];                      // vert [-1,0,1]
                const int blk = c >> 2;
                sX[im][blk]  += gx;  sXX[im][blk] += gx * gx;
                sY[im][blk]  += gy;  sYY[im][blk] += gy * gy;
            }
            hX2[im][c] = hX1[im][c];  hX1[im][c] = hX0;
            hB2[im][c] = hB1[im][c];  hB1[im][c] = hB0;
        }
    };

    // prologue: 3 rows in flight
    issue_row(0, Rb[0]);
    issue_row(1, Rb[1]);
    issue_row(2, Rb[2]);

#pragma unroll
    for (int i = 0; i < 18; ++i) {
        if (i + 3 < 18) issue_row(i + 3, Rb[(i + 3) & 3]);
        const int ahead = (i + 3 <= 17) ? 3 : (17 - i);
        if (ahead == 3)      waitv<3>();
        else if (ahead == 2) waitv<2>();
        else if (ahead == 1) waitv<1>();
        else                 waitv<0>();
        Row& R = Rb[i & 3];
        const float m = (i == 0) ? m0 : ((i == 17) ? m17 : 1.f);
        const bool emit = (i >= 2);
        consume_img(0, R.a0, R.a1, R.ea, m, emit);
        consume_img(1, R.b0, R.b1, R.eb, m, emit);
        if (i >= 5 && ((i - 5) & 3) == 0) finalize();
    }

    // wave reduction, one partial per wave
#pragma unroll
    for (int off = 32; off > 0; off >>= 1) loss += __shfl_down(loss, off);
    if (lane == 0) partial[wave] = loss;
}

__global__ __launch_bounds__(256) void gvl_final(const float* __restrict__ partial,
                                                 float* __restrict__ out) {
    int t = threadIdx.x;
    float s = 0.f;
#pragma unroll
    for (int i = 0; i < 8; ++i) s += partial[t + (i << 8)];
#pragma unroll
    for (int off = 32; off > 0; off >>= 1) s += __shfl_down(s, off);
    __shared__ float ws[4];
    if ((t & 63) == 0) ws[t >> 6] = s;
    __syncthreads();
    if (t == 0) out[0] = ws[0] + ws[1] + ws[2] + ws[3];
}

extern "C" void kernel_launch(void* const* d_in, const int* in_sizes, int n_in,
                              void* d_out, int out_size, void* d_ws, size_t ws_size,
                              hipStream_t stream) {
    const float* out_img = (const float*)d_in[0];
    const float* tgt_img = (const float*)d_in[1];
    float* partial = (float*)d_ws;   // 2048 floats = 8 KB
    gvl_main<<<512, 256, 0, stream>>>(out_img, tgt_img, partial);
    gvl_final<<<1, 256, 0, stream>>>(partial, (float*)d_out);
}